// Round 1
// baseline (938.919 us; speedup 1.0000x reference)
//
#include <hip/hip_runtime.h>

// GCN 2-layer: sigmoid( A_hat @ relu(A_hat @ (x@W1) + b1) @ W2 + b2 )
// A_hat = D^-1/2 (A + I) D^-1/2, deg counted over col (in-degree + 1).
//
// Pipeline (all fp32 except h1 stored bf16):
//   k_init   : zero cnt
//   k_count  : cnt[col]++ (int atomics)
//   k_scanA/B/C : exclusive scan -> offs; dis = rsqrt(cnt+1); reset cnt
//   k_fill   : CSR fill eidx[offs[col]+pos] = row  (int atomics)
//   k_gemm1  : h1 = bf16(x @ W1), MFMA 16x16x32 bf16, [N][52] padded
//   k_agg1   : per-node gather-sum of h1 rows, +self, +b1, relu, @W2 -> h2
//   k_agg2   : per-node gather-sum of h2 rows, +self, +b2, sigmoid -> out

#define N_NODES 100000
#define N_EDGES 3200000
#define IN_DIM  768
#define HID     50
#define HIDP    52      // pad to 13 float4-groups; pad cols are exact 0
#define SCAN_BLK 1024
#define NSCAN_BLKS 98   // 98*1024 = 100352 >= N_NODES
#define NPAD (NSCAN_BLKS * SCAN_BLK)

using s8v = __attribute__((ext_vector_type(8))) short;   // 8 x bf16
using f4v = __attribute__((ext_vector_type(4))) float;   // 4 x fp32

__device__ __forceinline__ short f2bf(float f) {
  union { float f; unsigned u; } v; v.f = f;
  unsigned r = (v.u + 0x7fffu + ((v.u >> 16) & 1u)) >> 16;  // RNE
  return (short)r;
}
__device__ __forceinline__ float bf2f(unsigned short u) {
  union { unsigned u; float f; } v; v.u = ((unsigned)u) << 16;
  return v.f;
}

// ---------------- degree / CSR build ----------------

__global__ void k_init(int* __restrict__ cnt) {
  int g = blockIdx.x * 256 + threadIdx.x;
  if (g < NPAD) cnt[g] = 0;
}

__global__ void k_count(const int* __restrict__ edges, int* __restrict__ cnt) {
  int e = blockIdx.x * 256 + threadIdx.x;
  if (e < N_EDGES) atomicAdd(&cnt[edges[N_EDGES + e]], 1);
}

__global__ void k_scanA(const int* __restrict__ cnt, int* __restrict__ offs,
                        int* __restrict__ bsum) {
  __shared__ int s[SCAN_BLK];
  int t = threadIdx.x;
  int g = blockIdx.x * SCAN_BLK + t;
  int v = (g < N_NODES) ? cnt[g] : 0;
  s[t] = v;
  __syncthreads();
  for (int off = 1; off < SCAN_BLK; off <<= 1) {
    int add = (t >= off) ? s[t - off] : 0;
    __syncthreads();
    s[t] += add;
    __syncthreads();
  }
  offs[g] = s[t] - v;                    // exclusive within block
  if (t == SCAN_BLK - 1) bsum[blockIdx.x] = s[t];
}

__global__ void k_scanB(int* __restrict__ bsum) {
  if (threadIdx.x == 0 && blockIdx.x == 0) {
    int acc = 0;
    for (int i = 0; i < NSCAN_BLKS; ++i) { int v = bsum[i]; bsum[i] = acc; acc += v; }
  }
}

__global__ void k_scanC(int* __restrict__ cnt, int* __restrict__ offs,
                        const int* __restrict__ bsum, float* __restrict__ dis) {
  int g = blockIdx.x * 256 + threadIdx.x;
  if (g < NPAD) {
    offs[g] += bsum[g >> 10];
    if (g < N_NODES) {
      dis[g] = rsqrtf((float)cnt[g] + 1.0f);  // +1 = self-loop
      cnt[g] = 0;                             // reuse as fill cursor
    }
  }
}

__global__ void k_fill(const int* __restrict__ edges, int* __restrict__ cnt,
                       const int* __restrict__ offs, int* __restrict__ eidx) {
  int e = blockIdx.x * 256 + threadIdx.x;
  if (e < N_EDGES) {
    int r = edges[e];
    int c = edges[N_EDGES + e];
    int p = atomicAdd(&cnt[c], 1);
    eidx[offs[c] + p] = r;
  }
}

// ---------------- GEMM1: h1 = bf16(x @ W1), [N][HIDP] ----------------
// block = 256 (4 waves), tile 64 rows x 64 cols (cols 50..63 zero-padded).
// A (x) loaded straight from global per-lane (no reuse across waves since
// the full output width fits one wave tile), W1 chunk staged in LDS^T.

__global__ __launch_bounds__(256) void k_gemm1(const float* __restrict__ x,
                                               const float* __restrict__ W1,
                                               unsigned short* __restrict__ h1) {
  __shared__ short BT[64][72];   // [n][k], stride 144 B (16B-aligned rows)
  int t = threadIdx.x;
  int wave = t >> 6, lane = t & 63;
  int col = lane & 15, quad = lane >> 4;
  int rb = blockIdx.x * 64 + wave * 16;
  int arow = rb + col;
  if (arow > N_NODES - 1) arow = N_NODES - 1;   // clamp; stores guarded
  const float* xrow = x + (size_t)arow * IN_DIM + quad * 8;

  f4v acc[4] = {f4v{0.f,0.f,0.f,0.f}, f4v{0.f,0.f,0.f,0.f},
                f4v{0.f,0.f,0.f,0.f}, f4v{0.f,0.f,0.f,0.f}};

  for (int chunk = 0; chunk < IN_DIM / 64; ++chunk) {
    int k0 = chunk * 64;
    __syncthreads();
    // stage W1[k0:k0+64, 0:64] transposed into BT[n][k] as bf16
    for (int e = t; e < 64 * 64; e += 256) {
      int k = e >> 6, n = e & 63;
      float v = (n < HID) ? W1[(k0 + k) * HID + n] : 0.f;
      BT[n][k] = f2bf(v);
    }
    __syncthreads();
    for (int kk = 0; kk < 64; kk += 32) {
      float4 va = *(const float4*)(xrow + k0 + kk);
      float4 vb = *(const float4*)(xrow + k0 + kk + 4);
      s8v a;
      a[0] = f2bf(va.x); a[1] = f2bf(va.y); a[2] = f2bf(va.z); a[3] = f2bf(va.w);
      a[4] = f2bf(vb.x); a[5] = f2bf(vb.y); a[6] = f2bf(vb.z); a[7] = f2bf(vb.w);
      s8v b0 = *(const s8v*)&BT[ 0 + col][kk + quad * 8];
      s8v b1 = *(const s8v*)&BT[16 + col][kk + quad * 8];
      s8v b2 = *(const s8v*)&BT[32 + col][kk + quad * 8];
      s8v b3 = *(const s8v*)&BT[48 + col][kk + quad * 8];
      acc[0] = __builtin_amdgcn_mfma_f32_16x16x32_bf16(a, b0, acc[0], 0, 0, 0);
      acc[1] = __builtin_amdgcn_mfma_f32_16x16x32_bf16(a, b1, acc[1], 0, 0, 0);
      acc[2] = __builtin_amdgcn_mfma_f32_16x16x32_bf16(a, b2, acc[2], 0, 0, 0);
      acc[3] = __builtin_amdgcn_mfma_f32_16x16x32_bf16(a, b3, acc[3], 0, 0, 0);
    }
  }
  // C/D layout: col = lane&15, row = quad*4 + reg  [m89/m91 verified]
  for (int nt = 0; nt < 4; ++nt) {
    int c = nt * 16 + col;
    if (c < HIDP) {
      for (int r = 0; r < 4; ++r) {
        int node = rb + quad * 4 + r;
        if (node < N_NODES)
          h1[(size_t)node * HIDP + c] = (unsigned short)f2bf(acc[nt][r]);
      }
    }
  }
}

// ---------------- layer-1 aggregate + bias + relu + GEMM2 ----------------
// 16 lanes per node; lane L handles channels 4L..4L+3 (L<13 active).

__global__ __launch_bounds__(256) void k_agg1(
    const unsigned short* __restrict__ h1, const int* __restrict__ eidx,
    const int* __restrict__ offs, const float* __restrict__ dis,
    const float* __restrict__ b1, const float* __restrict__ W2,
    float* __restrict__ h2) {
  __shared__ float W2s[2][HIDP];
  __shared__ float b1s[HIDP];
  int t = threadIdx.x;
  if (t < HIDP) {
    b1s[t] = (t < HID) ? b1[t] : 0.f;
    W2s[0][t] = (t < HID) ? W2[t * 2 + 0] : 0.f;
    W2s[1][t] = (t < HID) ? W2[t * 2 + 1] : 0.f;
  }
  __syncthreads();
  int g = t >> 4, L = t & 15;
  int n = blockIdx.x * 16 + g;
  if (n >= N_NODES) return;
  int start = offs[n];
  int end = (n == N_NODES - 1) ? N_EDGES : offs[n + 1];
  int base = L * 4;
  bool act = base < HIDP;   // lanes 13..15 idle
  float a0 = 0.f, a1 = 0.f, a2 = 0.f, a3 = 0.f;
  for (int i = start; i < end; ++i) {
    int idx = eidx[i];
    float d = dis[idx];
    if (act) {
      ushort4 u = *(const ushort4*)(h1 + (size_t)idx * HIDP + base);
      a0 += bf2f(u.x) * d; a1 += bf2f(u.y) * d;
      a2 += bf2f(u.z) * d; a3 += bf2f(u.w) * d;
    }
  }
  float p0 = 0.f, p1 = 0.f;
  if (act) {
    float dn = dis[n];
    ushort4 u = *(const ushort4*)(h1 + (size_t)n * HIDP + base);
    a0 = a0 * dn + bf2f(u.x) * dn * dn + b1s[base + 0];
    a1 = a1 * dn + bf2f(u.y) * dn * dn + b1s[base + 1];
    a2 = a2 * dn + bf2f(u.z) * dn * dn + b1s[base + 2];
    a3 = a3 * dn + bf2f(u.w) * dn * dn + b1s[base + 3];
    a0 = fmaxf(a0, 0.f); a1 = fmaxf(a1, 0.f);
    a2 = fmaxf(a2, 0.f); a3 = fmaxf(a3, 0.f);
    p0 = a0 * W2s[0][base] + a1 * W2s[0][base + 1] +
         a2 * W2s[0][base + 2] + a3 * W2s[0][base + 3];
    p1 = a0 * W2s[1][base] + a1 * W2s[1][base + 1] +
         a2 * W2s[1][base + 2] + a3 * W2s[1][base + 3];
  }
  for (int m = 8; m; m >>= 1) {
    p0 += __shfl_xor(p0, m, 16);
    p1 += __shfl_xor(p1, m, 16);
  }
  if (L == 0) {
    h2[(size_t)n * 2 + 0] = p0;
    h2[(size_t)n * 2 + 1] = p1;
  }
}

// ---------------- layer-2 aggregate + bias + sigmoid ----------------

__global__ __launch_bounds__(256) void k_agg2(
    const float* __restrict__ h2, const int* __restrict__ eidx,
    const int* __restrict__ offs, const float* __restrict__ dis,
    const float* __restrict__ b2, float* __restrict__ out) {
  int t = threadIdx.x;
  int g = t >> 4, L = t & 15;
  int n = blockIdx.x * 16 + g;
  if (n >= N_NODES) return;
  int start = offs[n];
  int end = (n == N_NODES - 1) ? N_EDGES : offs[n + 1];
  float a0 = 0.f, a1 = 0.f;
  for (int i = start + L; i < end; i += 16) {
    int idx = eidx[i];
    float d = dis[idx];
    float2 v = *(const float2*)(h2 + (size_t)idx * 2);
    a0 += v.x * d; a1 += v.y * d;
  }
  for (int m = 8; m; m >>= 1) {
    a0 += __shfl_xor(a0, m, 16);
    a1 += __shfl_xor(a1, m, 16);
  }
  if (L == 0) {
    float dn = dis[n];
    float2 v = *(const float2*)(h2 + (size_t)n * 2);
    float r0 = a0 * dn + v.x * dn * dn + b2[0];
    float r1 = a1 * dn + v.y * dn * dn + b2[1];
    out[(size_t)n * 2 + 0] = 1.f / (1.f + __expf(-r0));
    out[(size_t)n * 2 + 1] = 1.f / (1.f + __expf(-r1));
  }
}

// ---------------- launch ----------------

static inline size_t aln(size_t v) { return (v + 255) & ~(size_t)255; }

extern "C" void kernel_launch(void* const* d_in, const int* in_sizes, int n_in,
                              void* d_out, int out_size, void* d_ws, size_t ws_size,
                              hipStream_t stream) {
  const float* x     = (const float*)d_in[0];
  const int*   edges = (const int*)d_in[1];     // [2][E]: rows then cols
  const float* W1    = (const float*)d_in[2];   // [768][50]
  const float* b1    = (const float*)d_in[3];
  const float* W2    = (const float*)d_in[4];   // [50][2]
  const float* b2    = (const float*)d_in[5];
  float* out = (float*)d_out;

  char* p = (char*)d_ws;
  int* cnt  = (int*)p;            p += aln((size_t)NPAD * 4);
  int* offs = (int*)p;            p += aln((size_t)NPAD * 4);
  int* bsum = (int*)p;            p += aln((size_t)NSCAN_BLKS * 4);
  float* dis = (float*)p;         p += aln((size_t)N_NODES * 4);
  int* eidx = (int*)p;            p += aln((size_t)N_EDGES * 4);
  unsigned short* h1 = (unsigned short*)p; p += aln((size_t)N_NODES * HIDP * 2);
  float* h2 = (float*)p;          p += aln((size_t)N_NODES * 2 * 4);

  int gN   = (NPAD + 255) / 256;            // 392
  int gE   = (N_EDGES + 255) / 256;         // 12500
  int gMM  = (N_NODES + 63) / 64;           // 1563
  int gAgg = (N_NODES + 15) / 16;           // 6250

  k_init <<<gN, 256, 0, stream>>>(cnt);
  k_count<<<gE, 256, 0, stream>>>(edges, cnt);
  k_scanA<<<NSCAN_BLKS, SCAN_BLK, 0, stream>>>(cnt, offs, bsum);
  k_scanB<<<1, 64, 0, stream>>>(bsum);
  k_scanC<<<gN, 256, 0, stream>>>(cnt, offs, bsum, dis);
  k_fill <<<gE, 256, 0, stream>>>(edges, cnt, offs, eidx);
  k_gemm1<<<gMM, 256, 0, stream>>>(x, W1, h1);
  k_agg1 <<<gAgg, 256, 0, stream>>>(h1, eidx, offs, dis, b1, W2, h2);
  k_agg2 <<<gAgg, 256, 0, stream>>>(h2, eidx, offs, dis, b2, out);
}

// Round 2
// 839.190 us; speedup vs baseline: 1.1188x; 1.1188x over previous
//
#include <hip/hip_runtime.h>

// GCN 2-layer: sigmoid( A_hat @ relu(A_hat @ (x@W1) + b1) @ W2 + b2 )
// A_hat = D^-1/2 (A + I) D^-1/2.
//
// Key structure (round 2):
//  - k_wprep : W1 -> bf16 MFMA B-fragment order in global (L2-hot, grid-shared)
//  - k_gemm1 : barrier-free, LDS-free MFMA GEMM; h1s[n] = bf16(x@W1 * dis[n])
//  - k_agg1  : wave/node, 4 edge-ways x 13 channel-lanes, depth-2 prefetch,
//              fused +self, +b1, relu, @W2, *dis -> h2s (fp32 [N][2])
//  - k_agg2  : wave/node, 64-way edge stride, fused +self, +b2, sigmoid
//  - CSR build: memset + count + 3-phase scan (parallel) + fill

#define N_NODES 100000
#define N_EDGES 3200000
#define IN_DIM  768
#define HID     50
#define HIDP    52      // pad to 13 float4-groups; pad cols written as 0
#define SCAN_BLK 1024
#define NSCAN_BLKS 98   // 98*1024 = 100352 >= N_NODES
#define NPAD (NSCAN_BLKS * SCAN_BLK)
#define NKSTEP (IN_DIM / 32)   // 24 k-steps of 32

using s8v = __attribute__((ext_vector_type(8))) short;   // 8 x bf16
using f4v = __attribute__((ext_vector_type(4))) float;   // 4 x fp32

__device__ __forceinline__ short f2bf(float f) {
  union { float f; unsigned u; } v; v.f = f;
  unsigned r = (v.u + 0x7fffu + ((v.u >> 16) & 1u)) >> 16;  // RNE
  return (short)r;
}
__device__ __forceinline__ float bf2f(unsigned short u) {
  union { unsigned u; float f; } v; v.u = ((unsigned)u) << 16;
  return v.f;
}

// ---------------- degree / CSR build ----------------

__global__ void k_count(const int* __restrict__ edges, int* __restrict__ cnt) {
  int e = blockIdx.x * 256 + threadIdx.x;
  if (e < N_EDGES) atomicAdd(&cnt[edges[N_EDGES + e]], 1);
}

__global__ void k_scanA(const int* __restrict__ cnt, int* __restrict__ offs,
                        int* __restrict__ bsum) {
  __shared__ int s[SCAN_BLK];
  int t = threadIdx.x;
  int g = blockIdx.x * SCAN_BLK + t;
  int v = (g < N_NODES) ? cnt[g] : 0;
  s[t] = v;
  __syncthreads();
  for (int off = 1; off < SCAN_BLK; off <<= 1) {
    int add = (t >= off) ? s[t - off] : 0;
    __syncthreads();
    s[t] += add;
    __syncthreads();
  }
  offs[g] = s[t] - v;                    // exclusive within block
  if (t == SCAN_BLK - 1) bsum[blockIdx.x] = s[t];
}

__global__ void k_scanB(int* __restrict__ bsum) {
  __shared__ int s[128];
  int t = threadIdx.x;   // 128 threads
  int v = (t < NSCAN_BLKS) ? bsum[t] : 0;
  s[t] = v;
  __syncthreads();
  for (int off = 1; off < 128; off <<= 1) {
    int add = (t >= off) ? s[t - off] : 0;
    __syncthreads();
    s[t] += add;
    __syncthreads();
  }
  if (t < NSCAN_BLKS) bsum[t] = s[t] - v;   // exclusive
}

__global__ void k_scanC(int* __restrict__ cnt, int* __restrict__ offs,
                        const int* __restrict__ bsum, float* __restrict__ dis) {
  int g = blockIdx.x * 256 + threadIdx.x;
  if (g < NPAD) {
    offs[g] += bsum[g >> 10];
    if (g < N_NODES) {
      dis[g] = rsqrtf((float)cnt[g] + 1.0f);  // +1 = self-loop
      cnt[g] = 0;                             // reuse as fill cursor
    }
  }
}

__global__ void k_fill(const int* __restrict__ edges, int* __restrict__ cnt,
                       const int* __restrict__ offs, int* __restrict__ eidx) {
  int e = blockIdx.x * 256 + threadIdx.x;
  if (e < N_EDGES) {
    int r = edges[e];
    int c = edges[N_EDGES + e];
    int p = atomicAdd(&cnt[c], 1);
    eidx[offs[c] + p] = r;
  }
}

// ---------------- W1 -> B-fragment order ----------------
// Bfrag[((s*4+nt)*64 + lane)*8 + j] = bf16(W1[k][n]),
//   k = s*32 + (lane>>4)*8 + j, n = nt*16 + (lane&15), zero-padded n>=50.

__global__ void k_wprep(const float* __restrict__ W1, short* __restrict__ Bfrag) {
  int g = blockIdx.x * 256 + threadIdx.x;   // 24*256 = 6144
  int s = g >> 8, r = g & 255;
  int nt = r >> 6, l = r & 63;
  int col = l & 15, quad = l >> 4;
  int n = nt * 16 + col;
  int kb = s * 32 + quad * 8;
  s8v o;
#pragma unroll
  for (int j = 0; j < 8; ++j)
    o[j] = (n < HID) ? f2bf(W1[(size_t)(kb + j) * HID + n]) : (short)0;
  *(s8v*)(Bfrag + (size_t)g * 8) = o;
}

// ---------------- GEMM1: h1s = bf16((x @ W1) * dis), [N][HIDP] ----------------
// No LDS, no barriers. 4 waves/block, 16 rows/wave, full-width (64 col) tiles.

__global__ __launch_bounds__(256) void k_gemm1(const float* __restrict__ x,
                                               const short* __restrict__ Bfrag,
                                               const float* __restrict__ dis,
                                               unsigned short* __restrict__ h1) {
  int t = threadIdx.x;
  int wave = t >> 6, lane = t & 63;
  int col = lane & 15, quad = lane >> 4;
  int rb = blockIdx.x * 64 + wave * 16;
  int arow = rb + col;
  if (arow > N_NODES - 1) arow = N_NODES - 1;   // clamp; stores guarded
  const float* xrow = x + (size_t)arow * IN_DIM + quad * 8;
  const short* bbase = Bfrag + (size_t)lane * 8;

  f4v acc[4] = {f4v{0.f,0.f,0.f,0.f}, f4v{0.f,0.f,0.f,0.f},
                f4v{0.f,0.f,0.f,0.f}, f4v{0.f,0.f,0.f,0.f}};

#pragma unroll
  for (int s = 0; s < NKSTEP; ++s) {
    float4 va = *(const float4*)(xrow + s * 32);
    float4 vb = *(const float4*)(xrow + s * 32 + 4);
    s8v b0 = *(const s8v*)(bbase + (size_t)(s * 4 + 0) * 512);
    s8v b1 = *(const s8v*)(bbase + (size_t)(s * 4 + 1) * 512);
    s8v b2 = *(const s8v*)(bbase + (size_t)(s * 4 + 2) * 512);
    s8v b3 = *(const s8v*)(bbase + (size_t)(s * 4 + 3) * 512);
    s8v a;
    a[0] = f2bf(va.x); a[1] = f2bf(va.y); a[2] = f2bf(va.z); a[3] = f2bf(va.w);
    a[4] = f2bf(vb.x); a[5] = f2bf(vb.y); a[6] = f2bf(vb.z); a[7] = f2bf(vb.w);
    acc[0] = __builtin_amdgcn_mfma_f32_16x16x32_bf16(a, b0, acc[0], 0, 0, 0);
    acc[1] = __builtin_amdgcn_mfma_f32_16x16x32_bf16(a, b1, acc[1], 0, 0, 0);
    acc[2] = __builtin_amdgcn_mfma_f32_16x16x32_bf16(a, b2, acc[2], 0, 0, 0);
    acc[3] = __builtin_amdgcn_mfma_f32_16x16x32_bf16(a, b3, acc[3], 0, 0, 0);
  }

  // C/D layout: col = lane&15, row = quad*4 + reg  [m89/m91]
  int node0 = rb + quad * 4;
  float dd[4];
#pragma unroll
  for (int r = 0; r < 4; ++r)
    dd[r] = (node0 + r < N_NODES) ? dis[node0 + r] : 0.f;
#pragma unroll
  for (int nt = 0; nt < 4; ++nt) {
    int c = nt * 16 + col;
    if (c < HIDP) {
#pragma unroll
      for (int r = 0; r < 4; ++r) {
        int node = node0 + r;
        if (node < N_NODES)
          h1[(size_t)node * HIDP + c] = (unsigned short)f2bf(acc[nt][r] * dd[r]);
      }
    }
  }
}

// ---------------- layer-1 aggregate + bias + relu + GEMM2 ----------------
// 1 wave per node: 4 edge-ways x 16 channel-lanes (13 active, 4 ch each).
// h1 rows are pre-scaled by dis => plain gather-sum, no per-edge dis.

__global__ __launch_bounds__(256) void k_agg1(
    const unsigned short* __restrict__ h1, const int* __restrict__ eidx,
    const int* __restrict__ offs, const float* __restrict__ dis,
    const float* __restrict__ b1, const float* __restrict__ W2,
    float* __restrict__ h2s) {
  __shared__ float W2s[2][64];
  __shared__ float b1s[64];
  int t = threadIdx.x;
  if (t < 64) {
    b1s[t] = (t < HID) ? b1[t] : 0.f;
    W2s[0][t] = (t < HID) ? W2[t * 2 + 0] : 0.f;
    W2s[1][t] = (t < HID) ? W2[t * 2 + 1] : 0.f;
  }
  __syncthreads();
  int wave = t >> 6, lane = t & 63;
  int n = blockIdx.x * 4 + wave;
  if (n >= N_NODES) return;
  int way = lane >> 4, L = lane & 15;
  int base = L * 4;
  bool actC = base < HIDP;           // channel lane active
  int baseS = actC ? base : 0;       // safe address for idle lanes
  int start = offs[n];
  int end = (n == N_NODES - 1) ? N_EDGES : offs[n + 1];

  float a0 = 0.f, a1 = 0.f, a2 = 0.f, a3 = 0.f;
  // depth-2 software pipeline: prefetch eidx and h1-gather one iter ahead
  int i  = start + way;
  int idx  = (i  < end) ? eidx[i]  : n;
  ushort4 u = *(const ushort4*)(h1 + (size_t)idx * HIDP + baseS);
  int i2 = i + 4;
  int idx2 = (i2 < end) ? eidx[i2] : n;
  while (i < end) {
    ushort4 u2 = *(const ushort4*)(h1 + (size_t)idx2 * HIDP + baseS);
    int i3 = i2 + 4;
    int idx3 = (i3 < end) ? eidx[i3] : n;
    a0 += bf2f(u.x); a1 += bf2f(u.y); a2 += bf2f(u.z); a3 += bf2f(u.w);
    u = u2; idx2 = idx3; i = i2; i2 = i3;
  }

  // reduce across the 4 edge-ways (all lanes participate)
  a0 += __shfl_xor(a0, 16); a0 += __shfl_xor(a0, 32);
  a1 += __shfl_xor(a1, 16); a1 += __shfl_xor(a1, 32);
  a2 += __shfl_xor(a2, 16); a2 += __shfl_xor(a2, 32);
  a3 += __shfl_xor(a3, 16); a3 += __shfl_xor(a3, 32);

  float p0 = 0.f, p1 = 0.f;
  if (actC && way == 0) {
    float dn = dis[n];
    ushort4 us = *(const ushort4*)(h1 + (size_t)n * HIDP + base);  // self (pre-scaled)
    float s0 = (a0 + bf2f(us.x)) * dn + b1s[base + 0];
    float s1 = (a1 + bf2f(us.y)) * dn + b1s[base + 1];
    float s2 = (a2 + bf2f(us.z)) * dn + b1s[base + 2];
    float s3 = (a3 + bf2f(us.w)) * dn + b1s[base + 3];
    s0 = fmaxf(s0, 0.f); s1 = fmaxf(s1, 0.f);
    s2 = fmaxf(s2, 0.f); s3 = fmaxf(s3, 0.f);
    p0 = s0 * W2s[0][base] + s1 * W2s[0][base + 1] +
         s2 * W2s[0][base + 2] + s3 * W2s[0][base + 3];
    p1 = s0 * W2s[1][base] + s1 * W2s[1][base + 1] +
         s2 * W2s[1][base + 2] + s3 * W2s[1][base + 3];
  }
  // reduce across channel lanes (within way 0's 16-group)
  for (int m = 8; m; m >>= 1) {
    p0 += __shfl_xor(p0, m, 16);
    p1 += __shfl_xor(p1, m, 16);
  }
  if (lane == 0) {
    float dn = dis[n];
    h2s[(size_t)n * 2 + 0] = p0 * dn;   // pre-scale for layer 2
    h2s[(size_t)n * 2 + 1] = p1 * dn;
  }
}

// ---------------- layer-2 aggregate + bias + sigmoid ----------------
// 1 wave per node, 64-way edge stride (deg~33 -> typically 1 gather round).

__global__ __launch_bounds__(256) void k_agg2(
    const float* __restrict__ h2s, const int* __restrict__ eidx,
    const int* __restrict__ offs, const float* __restrict__ dis,
    const float* __restrict__ b2, float* __restrict__ out) {
  int t = threadIdx.x;
  int wave = t >> 6, lane = t & 63;
  int n = blockIdx.x * 4 + wave;
  if (n >= N_NODES) return;
  int start = offs[n];
  int end = (n == N_NODES - 1) ? N_EDGES : offs[n + 1];
  float s0 = 0.f, s1 = 0.f;
  for (int i = start + lane; i < end; i += 64) {
    int idx = eidx[i];
    float2 v = *(const float2*)(h2s + (size_t)idx * 2);
    s0 += v.x; s1 += v.y;
  }
  for (int m = 32; m; m >>= 1) {
    s0 += __shfl_xor(s0, m);
    s1 += __shfl_xor(s1, m);
  }
  if (lane == 0) {
    float dn = dis[n];
    float2 v = *(const float2*)(h2s + (size_t)n * 2);
    float r0 = (s0 + v.x) * dn + b2[0];
    float r1 = (s1 + v.y) * dn + b2[1];
    out[(size_t)n * 2 + 0] = 1.f / (1.f + __expf(-r0));
    out[(size_t)n * 2 + 1] = 1.f / (1.f + __expf(-r1));
  }
}

// ---------------- launch ----------------

static inline size_t aln(size_t v) { return (v + 255) & ~(size_t)255; }

extern "C" void kernel_launch(void* const* d_in, const int* in_sizes, int n_in,
                              void* d_out, int out_size, void* d_ws, size_t ws_size,
                              hipStream_t stream) {
  const float* x     = (const float*)d_in[0];
  const int*   edges = (const int*)d_in[1];     // [2][E]: rows then cols
  const float* W1    = (const float*)d_in[2];   // [768][50]
  const float* b1    = (const float*)d_in[3];
  const float* W2    = (const float*)d_in[4];   // [50][2]
  const float* b2    = (const float*)d_in[5];
  float* out = (float*)d_out;

  char* p = (char*)d_ws;
  int* cnt  = (int*)p;            p += aln((size_t)NPAD * 4);
  int* offs = (int*)p;            p += aln((size_t)NPAD * 4);
  int* bsum = (int*)p;            p += aln((size_t)NSCAN_BLKS * 4);
  float* dis = (float*)p;         p += aln((size_t)N_NODES * 4);
  int* eidx = (int*)p;            p += aln((size_t)N_EDGES * 4);
  short* Bfrag = (short*)p;       p += aln((size_t)NKSTEP * 4 * 64 * 8 * 2);
  unsigned short* h1 = (unsigned short*)p; p += aln((size_t)N_NODES * HIDP * 2);
  float* h2s = (float*)p;         p += aln((size_t)N_NODES * 2 * 4);

  int gN   = (NPAD + 255) / 256;            // 392
  int gE   = (N_EDGES + 255) / 256;         // 12500
  int gMM  = (N_NODES + 63) / 64;           // 1563
  int gW   = (N_NODES + 3) / 4;             // 25000 (wave per node)

  hipMemsetAsync(cnt, 0, (size_t)NPAD * 4, stream);
  k_count<<<gE, 256, 0, stream>>>(edges, cnt);
  k_scanA<<<NSCAN_BLKS, SCAN_BLK, 0, stream>>>(cnt, offs, bsum);
  k_scanB<<<1, 128, 0, stream>>>(bsum);
  k_scanC<<<gN, 256, 0, stream>>>(cnt, offs, bsum, dis);
  k_fill <<<gE, 256, 0, stream>>>(edges, cnt, offs, eidx);
  k_wprep<<<NKSTEP, 256, 0, stream>>>(W1, Bfrag);
  k_gemm1<<<gMM, 256, 0, stream>>>(x, Bfrag, dis, h1);
  k_agg1 <<<gW, 256, 0, stream>>>(h1, eidx, offs, dis, b1, W2, h2s);
  k_agg2 <<<gW, 256, 0, stream>>>(h2s, eidx, offs, dis, b2, out);
}

// Round 3
// 780.682 us; speedup vs baseline: 1.2027x; 1.0749x over previous
//
#include <hip/hip_runtime.h>

// GCN 2-layer: sigmoid( A_hat @ relu(A_hat @ (x@W1) + b1) @ W2 + b2 )
// A_hat = D^-1/2 (A + I) D^-1/2.
//
// Round 3 changes:
//  - k_count also records pos[e] (slot within dst bucket) -> k_fill is
//    atomic-free pure load->store (no atomic->scatter dependency chain)
//  - k_gemm1: 32 rows/wave (two 16-row MFMA tiles sharing B-frags) for 2x
//    memory-level parallelism on the x stream
//  - scanC no longer resets cnt (no fill cursor needed)

#define N_NODES 100000
#define N_EDGES 3200000
#define IN_DIM  768
#define HID     50
#define HIDP    52      // pad to 13 float4-groups; pad cols written as 0
#define SCAN_BLK 1024
#define NSCAN_BLKS 98   // 98*1024 = 100352 >= N_NODES
#define NPAD (NSCAN_BLKS * SCAN_BLK)
#define NKSTEP (IN_DIM / 32)   // 24 k-steps of 32

using s8v = __attribute__((ext_vector_type(8))) short;   // 8 x bf16
using f4v = __attribute__((ext_vector_type(4))) float;   // 4 x fp32

__device__ __forceinline__ short f2bf(float f) {
  union { float f; unsigned u; } v; v.f = f;
  unsigned r = (v.u + 0x7fffu + ((v.u >> 16) & 1u)) >> 16;  // RNE
  return (short)r;
}
__device__ __forceinline__ float bf2f(unsigned short u) {
  union { unsigned u; float f; } v; v.u = ((unsigned)u) << 16;
  return v.f;
}

// ---------------- degree / CSR build ----------------

__global__ void k_count(const int* __restrict__ edges, int* __restrict__ cnt,
                        int* __restrict__ pos) {
  int e = blockIdx.x * 256 + threadIdx.x;
  if (e < N_EDGES) pos[e] = atomicAdd(&cnt[edges[N_EDGES + e]], 1);
}

__global__ void k_scanA(const int* __restrict__ cnt, int* __restrict__ offs,
                        int* __restrict__ bsum) {
  __shared__ int s[SCAN_BLK];
  int t = threadIdx.x;
  int g = blockIdx.x * SCAN_BLK + t;
  int v = (g < N_NODES) ? cnt[g] : 0;
  s[t] = v;
  __syncthreads();
  for (int off = 1; off < SCAN_BLK; off <<= 1) {
    int add = (t >= off) ? s[t - off] : 0;
    __syncthreads();
    s[t] += add;
    __syncthreads();
  }
  offs[g] = s[t] - v;                    // exclusive within block
  if (t == SCAN_BLK - 1) bsum[blockIdx.x] = s[t];
}

__global__ void k_scanB(int* __restrict__ bsum) {
  __shared__ int s[128];
  int t = threadIdx.x;   // 128 threads
  int v = (t < NSCAN_BLKS) ? bsum[t] : 0;
  s[t] = v;
  __syncthreads();
  for (int off = 1; off < 128; off <<= 1) {
    int add = (t >= off) ? s[t - off] : 0;
    __syncthreads();
    s[t] += add;
    __syncthreads();
  }
  if (t < NSCAN_BLKS) bsum[t] = s[t] - v;   // exclusive
}

__global__ void k_scanC(const int* __restrict__ cnt, int* __restrict__ offs,
                        const int* __restrict__ bsum, float* __restrict__ dis) {
  int g = blockIdx.x * 256 + threadIdx.x;
  if (g < NPAD) {
    offs[g] += bsum[g >> 10];
    if (g < N_NODES)
      dis[g] = rsqrtf((float)cnt[g] + 1.0f);  // +1 = self-loop
  }
}

__global__ void k_fill(const int* __restrict__ edges, const int* __restrict__ pos,
                       const int* __restrict__ offs, int* __restrict__ eidx) {
  int e = blockIdx.x * 256 + threadIdx.x;
  if (e < N_EDGES) {
    int c = edges[N_EDGES + e];
    eidx[offs[c] + pos[e]] = edges[e];
  }
}

// ---------------- W1 -> B-fragment order ----------------
// Bfrag[((s*4+nt)*64 + lane)*8 + j] = bf16(W1[k][n]),
//   k = s*32 + (lane>>4)*8 + j, n = nt*16 + (lane&15), zero-padded n>=50.

__global__ void k_wprep(const float* __restrict__ W1, short* __restrict__ Bfrag) {
  int g = blockIdx.x * 256 + threadIdx.x;   // 24*256 = 6144
  int s = g >> 8, r = g & 255;
  int nt = r >> 6, l = r & 63;
  int col = l & 15, quad = l >> 4;
  int n = nt * 16 + col;
  int kb = s * 32 + quad * 8;
  s8v o;
#pragma unroll
  for (int j = 0; j < 8; ++j)
    o[j] = (n < HID) ? f2bf(W1[(size_t)(kb + j) * HID + n]) : (short)0;
  *(s8v*)(Bfrag + (size_t)g * 8) = o;
}

// ---------------- GEMM1: h1s = bf16((x @ W1) * dis), [N][HIDP] ----------------
// No LDS, no barriers. 4 waves/block, 32 rows/wave (2 MFMA row-tiles sharing
// B fragments), full-width (64 col) tiles.

__global__ __launch_bounds__(256) void k_gemm1(const float* __restrict__ x,
                                               const short* __restrict__ Bfrag,
                                               const float* __restrict__ dis,
                                               unsigned short* __restrict__ h1) {
  int t = threadIdx.x;
  int wave = t >> 6, lane = t & 63;
  int col = lane & 15, quad = lane >> 4;
  int rb = blockIdx.x * 128 + wave * 32;
  int arow0 = rb + col;
  int arow1 = rb + 16 + col;
  if (arow0 > N_NODES - 1) arow0 = N_NODES - 1;   // clamp; stores guarded
  if (arow1 > N_NODES - 1) arow1 = N_NODES - 1;
  const float* xrow0 = x + (size_t)arow0 * IN_DIM + quad * 8;
  const float* xrow1 = x + (size_t)arow1 * IN_DIM + quad * 8;
  const short* bbase = Bfrag + (size_t)lane * 8;

  f4v acc[8] = {f4v{0.f,0.f,0.f,0.f}, f4v{0.f,0.f,0.f,0.f},
                f4v{0.f,0.f,0.f,0.f}, f4v{0.f,0.f,0.f,0.f},
                f4v{0.f,0.f,0.f,0.f}, f4v{0.f,0.f,0.f,0.f},
                f4v{0.f,0.f,0.f,0.f}, f4v{0.f,0.f,0.f,0.f}};

#pragma unroll
  for (int s = 0; s < NKSTEP; ++s) {
    float4 va0 = *(const float4*)(xrow0 + s * 32);
    float4 vb0 = *(const float4*)(xrow0 + s * 32 + 4);
    float4 va1 = *(const float4*)(xrow1 + s * 32);
    float4 vb1 = *(const float4*)(xrow1 + s * 32 + 4);
    s8v b0 = *(const s8v*)(bbase + (size_t)(s * 4 + 0) * 512);
    s8v b1 = *(const s8v*)(bbase + (size_t)(s * 4 + 1) * 512);
    s8v b2 = *(const s8v*)(bbase + (size_t)(s * 4 + 2) * 512);
    s8v b3 = *(const s8v*)(bbase + (size_t)(s * 4 + 3) * 512);
    s8v a0, a1;
    a0[0] = f2bf(va0.x); a0[1] = f2bf(va0.y); a0[2] = f2bf(va0.z); a0[3] = f2bf(va0.w);
    a0[4] = f2bf(vb0.x); a0[5] = f2bf(vb0.y); a0[6] = f2bf(vb0.z); a0[7] = f2bf(vb0.w);
    a1[0] = f2bf(va1.x); a1[1] = f2bf(va1.y); a1[2] = f2bf(va1.z); a1[3] = f2bf(va1.w);
    a1[4] = f2bf(vb1.x); a1[5] = f2bf(vb1.y); a1[6] = f2bf(vb1.z); a1[7] = f2bf(vb1.w);
    acc[0] = __builtin_amdgcn_mfma_f32_16x16x32_bf16(a0, b0, acc[0], 0, 0, 0);
    acc[1] = __builtin_amdgcn_mfma_f32_16x16x32_bf16(a0, b1, acc[1], 0, 0, 0);
    acc[2] = __builtin_amdgcn_mfma_f32_16x16x32_bf16(a0, b2, acc[2], 0, 0, 0);
    acc[3] = __builtin_amdgcn_mfma_f32_16x16x32_bf16(a0, b3, acc[3], 0, 0, 0);
    acc[4] = __builtin_amdgcn_mfma_f32_16x16x32_bf16(a1, b0, acc[4], 0, 0, 0);
    acc[5] = __builtin_amdgcn_mfma_f32_16x16x32_bf16(a1, b1, acc[5], 0, 0, 0);
    acc[6] = __builtin_amdgcn_mfma_f32_16x16x32_bf16(a1, b2, acc[6], 0, 0, 0);
    acc[7] = __builtin_amdgcn_mfma_f32_16x16x32_bf16(a1, b3, acc[7], 0, 0, 0);
  }

  // C/D layout: col = lane&15, row = quad*4 + reg  [m89/m91]
#pragma unroll
  for (int half = 0; half < 2; ++half) {
    int node0 = rb + half * 16 + quad * 4;
    float dd[4];
#pragma unroll
    for (int r = 0; r < 4; ++r)
      dd[r] = (node0 + r < N_NODES) ? dis[node0 + r] : 0.f;
#pragma unroll
    for (int nt = 0; nt < 4; ++nt) {
      int c = nt * 16 + col;
      if (c < HIDP) {
#pragma unroll
        for (int r = 0; r < 4; ++r) {
          int node = node0 + r;
          if (node < N_NODES)
            h1[(size_t)node * HIDP + c] =
                (unsigned short)f2bf(acc[half * 4 + nt][r] * dd[r]);
        }
      }
    }
  }
}

// ---------------- layer-1 aggregate + bias + relu + GEMM2 ----------------
// 1 wave per node: 4 edge-ways x 16 channel-lanes (13 active, 4 ch each).
// h1 rows are pre-scaled by dis => plain gather-sum, no per-edge dis.

__global__ __launch_bounds__(256) void k_agg1(
    const unsigned short* __restrict__ h1, const int* __restrict__ eidx,
    const int* __restrict__ offs, const float* __restrict__ dis,
    const float* __restrict__ b1, const float* __restrict__ W2,
    float* __restrict__ h2s) {
  __shared__ float W2s[2][64];
  __shared__ float b1s[64];
  int t = threadIdx.x;
  if (t < 64) {
    b1s[t] = (t < HID) ? b1[t] : 0.f;
    W2s[0][t] = (t < HID) ? W2[t * 2 + 0] : 0.f;
    W2s[1][t] = (t < HID) ? W2[t * 2 + 1] : 0.f;
  }
  __syncthreads();
  int wave = t >> 6, lane = t & 63;
  int n = blockIdx.x * 4 + wave;
  if (n >= N_NODES) return;
  int way = lane >> 4, L = lane & 15;
  int base = L * 4;
  bool actC = base < HIDP;           // channel lane active
  int baseS = actC ? base : 0;       // safe address for idle lanes
  int start = offs[n];
  int end = (n == N_NODES - 1) ? N_EDGES : offs[n + 1];

  float a0 = 0.f, a1 = 0.f, a2 = 0.f, a3 = 0.f;
  // depth-2 software pipeline: prefetch eidx and h1-gather one iter ahead
  int i  = start + way;
  int idx  = (i  < end) ? eidx[i]  : n;
  ushort4 u = *(const ushort4*)(h1 + (size_t)idx * HIDP + baseS);
  int i2 = i + 4;
  int idx2 = (i2 < end) ? eidx[i2] : n;
  while (i < end) {
    ushort4 u2 = *(const ushort4*)(h1 + (size_t)idx2 * HIDP + baseS);
    int i3 = i2 + 4;
    int idx3 = (i3 < end) ? eidx[i3] : n;
    a0 += bf2f(u.x); a1 += bf2f(u.y); a2 += bf2f(u.z); a3 += bf2f(u.w);
    u = u2; idx2 = idx3; i = i2; i2 = i3;
  }

  // reduce across the 4 edge-ways (all lanes participate)
  a0 += __shfl_xor(a0, 16); a0 += __shfl_xor(a0, 32);
  a1 += __shfl_xor(a1, 16); a1 += __shfl_xor(a1, 32);
  a2 += __shfl_xor(a2, 16); a2 += __shfl_xor(a2, 32);
  a3 += __shfl_xor(a3, 16); a3 += __shfl_xor(a3, 32);

  float p0 = 0.f, p1 = 0.f;
  if (actC && way == 0) {
    float dn = dis[n];
    ushort4 us = *(const ushort4*)(h1 + (size_t)n * HIDP + base);  // self (pre-scaled)
    float s0 = (a0 + bf2f(us.x)) * dn + b1s[base + 0];
    float s1 = (a1 + bf2f(us.y)) * dn + b1s[base + 1];
    float s2 = (a2 + bf2f(us.z)) * dn + b1s[base + 2];
    float s3 = (a3 + bf2f(us.w)) * dn + b1s[base + 3];
    s0 = fmaxf(s0, 0.f); s1 = fmaxf(s1, 0.f);
    s2 = fmaxf(s2, 0.f); s3 = fmaxf(s3, 0.f);
    p0 = s0 * W2s[0][base] + s1 * W2s[0][base + 1] +
         s2 * W2s[0][base + 2] + s3 * W2s[0][base + 3];
    p1 = s0 * W2s[1][base] + s1 * W2s[1][base + 1] +
         s2 * W2s[1][base + 2] + s3 * W2s[1][base + 3];
  }
  // reduce across channel lanes (within way 0's 16-group)
  for (int m = 8; m; m >>= 1) {
    p0 += __shfl_xor(p0, m, 16);
    p1 += __shfl_xor(p1, m, 16);
  }
  if (lane == 0) {
    float dn = dis[n];
    h2s[(size_t)n * 2 + 0] = p0 * dn;   // pre-scale for layer 2
    h2s[(size_t)n * 2 + 1] = p1 * dn;
  }
}

// ---------------- layer-2 aggregate + bias + sigmoid ----------------
// 1 wave per node, 64-way edge stride (deg~33 -> typically 1 gather round).

__global__ __launch_bounds__(256) void k_agg2(
    const float* __restrict__ h2s, const int* __restrict__ eidx,
    const int* __restrict__ offs, const float* __restrict__ dis,
    const float* __restrict__ b2, float* __restrict__ out) {
  int t = threadIdx.x;
  int wave = t >> 6, lane = t & 63;
  int n = blockIdx.x * 4 + wave;
  if (n >= N_NODES) return;
  int start = offs[n];
  int end = (n == N_NODES - 1) ? N_EDGES : offs[n + 1];
  float s0 = 0.f, s1 = 0.f;
  for (int i = start + lane; i < end; i += 64) {
    int idx = eidx[i];
    float2 v = *(const float2*)(h2s + (size_t)idx * 2);
    s0 += v.x; s1 += v.y;
  }
  for (int m = 32; m; m >>= 1) {
    s0 += __shfl_xor(s0, m);
    s1 += __shfl_xor(s1, m);
  }
  if (lane == 0) {
    float dn = dis[n];
    float2 v = *(const float2*)(h2s + (size_t)n * 2);
    float r0 = (s0 + v.x) * dn + b2[0];
    float r1 = (s1 + v.y) * dn + b2[1];
    out[(size_t)n * 2 + 0] = 1.f / (1.f + __expf(-r0));
    out[(size_t)n * 2 + 1] = 1.f / (1.f + __expf(-r1));
  }
}

// ---------------- launch ----------------

static inline size_t aln(size_t v) { return (v + 255) & ~(size_t)255; }

extern "C" void kernel_launch(void* const* d_in, const int* in_sizes, int n_in,
                              void* d_out, int out_size, void* d_ws, size_t ws_size,
                              hipStream_t stream) {
  const float* x     = (const float*)d_in[0];
  const int*   edges = (const int*)d_in[1];     // [2][E]: rows then cols
  const float* W1    = (const float*)d_in[2];   // [768][50]
  const float* b1    = (const float*)d_in[3];
  const float* W2    = (const float*)d_in[4];   // [50][2]
  const float* b2    = (const float*)d_in[5];
  float* out = (float*)d_out;

  char* p = (char*)d_ws;
  int* cnt  = (int*)p;            p += aln((size_t)NPAD * 4);
  int* offs = (int*)p;            p += aln((size_t)NPAD * 4);
  int* bsum = (int*)p;            p += aln((size_t)NSCAN_BLKS * 4);
  float* dis = (float*)p;         p += aln((size_t)N_NODES * 4);
  int* eidx = (int*)p;            p += aln((size_t)N_EDGES * 4);
  int* pos  = (int*)p;            p += aln((size_t)N_EDGES * 4);
  short* Bfrag = (short*)p;       p += aln((size_t)NKSTEP * 4 * 64 * 8 * 2);
  unsigned short* h1 = (unsigned short*)p; p += aln((size_t)N_NODES * HIDP * 2);
  float* h2s = (float*)p;         p += aln((size_t)N_NODES * 2 * 4);

  int gN   = (NPAD + 255) / 256;            // 392
  int gE   = (N_EDGES + 255) / 256;         // 12500
  int gMM  = (N_NODES + 127) / 128;         // 782
  int gW   = (N_NODES + 3) / 4;             // 25000 (wave per node)

  hipMemsetAsync(cnt, 0, (size_t)N_NODES * 4, stream);
  k_count<<<gE, 256, 0, stream>>>(edges, cnt, pos);
  k_scanA<<<NSCAN_BLKS, SCAN_BLK, 0, stream>>>(cnt, offs, bsum);
  k_scanB<<<1, 128, 0, stream>>>(bsum);
  k_scanC<<<gN, 256, 0, stream>>>(cnt, offs, bsum, dis);
  k_fill <<<gE, 256, 0, stream>>>(edges, pos, offs, eidx);
  k_wprep<<<NKSTEP, 256, 0, stream>>>(W1, Bfrag);
  k_gemm1<<<gMM, 256, 0, stream>>>(x, Bfrag, dis, h1);
  k_agg1 <<<gW, 256, 0, stream>>>(h1, eidx, offs, dis, b1, W2, h2s);
  k_agg2 <<<gW, 256, 0, stream>>>(h2s, eidx, offs, dis, b2, out);
}